// Round 10
// baseline (485.747 us; speedup 1.0000x reference)
//
#include <hip/hip_runtime.h>
#include <stdint.h>

#define N_ATOMS 100000
#define NS 4
#define NE 8
#define D0 384
#define D1 160
#define D2 128
#define D3 96
#define TW 32                                 // atoms per wave tile
#define BUCKET_CAP 32768

// ---- workspace layout (bytes) ----
#define IDX_OFF_B 256
#define IDX_CAP (NS*BUCKET_CAP)               // 131072 ints
#define W1B_OFF (IDX_OFF_B + IDX_CAP*4)
#define W1_TOT (NS*NE*D0*D1)
#define W2_TOT (NS*NE*D1*D2)
#define W3_TOT (NS*NE*D2*D3)
#define W2B_OFF (W1B_OFF + W1_TOT*2)
#define W3B_OFF (W2B_OFF + W2_TOT*2)

// LDS strides (halves) — measured 0 bank conflicts with these (R2/R7).
#define S1STR 172
#define S2STR 140

// residency plan: 768 phase-1 blocks (4 waves * 4 consecutive same-species
// tiles each) + 112 tail blocks running leftover tiles as (tile, e) units.
#define P1TILES 3072
#define P1BLOCKS 768
#define TAILBLOCKS 112                        // 112*4 = 448 = 56*8 units
#define GRID_MLP (P1BLOCKS + TAILBLOCKS)

typedef __attribute__((ext_vector_type(8))) _Float16 h8v;
typedef __attribute__((ext_vector_type(4))) float f4v;

__device__ __forceinline__ unsigned short f2h(float x){
    _Float16 h = (_Float16)x;
    return *(unsigned short*)&h;
}

// jax.nn.celu(x, 0.1) = x>0 ? x : 0.1*expm1(x/0.1)
__device__ __forceinline__ float celu01(float v){
    return v > 0.f ? v : 0.1f * (__expf(fminf(v, 0.f) * 10.f) - 1.f);
}

__global__ void k_init(int* hdr, float* out){
    int i = threadIdx.x;
    if (i < 32) hdr[i] = 0;
    if (i == 0) out[0] = 0.f;
}

__global__ __launch_bounds__(256) void k_scatter(const int* __restrict__ species,
                                                 int* __restrict__ hdr,
                                                 int* __restrict__ idx){
    __shared__ int lc[NS];
    __shared__ int lb[NS];
    int tid = threadIdx.x;
    if (tid < NS) lc[tid] = 0;
    __syncthreads();
    int i = blockIdx.x * 256 + tid;
    int s = 0, r = 0;
    bool valid = (i < N_ATOMS);
    if (valid){
        s = species[i];
        r = atomicAdd(&lc[s], 1);
    }
    __syncthreads();
    if (tid < NS) lb[tid] = atomicAdd(&hdr[tid], lc[tid]);
    __syncthreads();
    if (valid) idx[s * BUCKET_CAP + lb[s] + r] = i;
}

// W1..W3 fp32 -> fp16 in MFMA-B-fragment order: [net][nt][kt][lane][j]
__global__ void k_convert(const float* __restrict__ W1, const float* __restrict__ W2,
                          const float* __restrict__ W3,
                          unsigned short* __restrict__ W1b, unsigned short* __restrict__ W2b,
                          unsigned short* __restrict__ W3b){
    int i = blockIdx.x * blockDim.x + threadIdx.x;
    if (i < W1_TOT){
        int net = i / (D0*D1);
        int r   = i % (D0*D1);
        int j = r & 7, lane = (r >> 3) & 63, kt = (r >> 9) % 12, nt = r / 6144;
        int k = kt*32 + (lane >> 4)*8 + j;
        int n = nt*16 + (lane & 15);
        W1b[i] = f2h(W1[(net*D0 + k)*D1 + n]);
    } else if (i < W1_TOT + W2_TOT){
        int i2 = i - W1_TOT;
        int net = i2 / (D1*D2);
        int r   = i2 % (D1*D2);
        int j = r & 7, lane = (r >> 3) & 63, kt = (r >> 9) % 5, nt = r / 2560;
        int k = kt*32 + (lane >> 4)*8 + j;
        int n = nt*16 + (lane & 15);
        W2b[i2] = f2h(W2[(net*D1 + k)*D2 + n]);
    } else if (i < W1_TOT + W2_TOT + W3_TOT){
        int i3 = i - W1_TOT - W2_TOT;
        int net = i3 / (D2*D3);
        int r   = i3 % (D2*D3);
        int j = r & 7, lane = (r >> 3) & 63, kt = (r >> 9) % 4, nt = r / 2048;
        int k = kt*32 + (lane >> 4)*8 + j;
        int n = nt*16 + (lane & 15);
        W3b[i3] = f2h(W3[(net*D2 + k)*D3 + n]);
    }
}

// Barrier-free MLP (R7 body, measured 336.8us): one WAVE = one 32-atom tile.
// R10 delta: layer-1 B prefetch is a 3x6-fragment half-nt rotation (72 VGPRs
// static) instead of 2x12 ping-pong (96) -- goal: kill the ~23MB scratch
// spill, which is suspected of THROTTLING occupancy to 2 blocks/CU (scratch
// backing limits concurrent waves). 6-12 loads stay in flight.
// Proven-load-bearing: __launch_bounds__(256,2) (min-waves>=3 -> 84 VGPR ->
// 164MB spill, R1/R4); plain cached loads (NT -> 4x HBM amplification, R6);
// no per-e barrier (R8: +7us); pad-strides 172/140 (0 conflicts); scalar
// bias prefetched 1 nt ahead (R7: -22us; f4v bias regs -> +16MB spill, R9).
__global__ __launch_bounds__(256, 2) void k_mlp(
    const float* __restrict__ aev, const int* __restrict__ hdr, const int* __restrict__ idx,
    const unsigned short* __restrict__ W1b, const unsigned short* __restrict__ W2b,
    const unsigned short* __restrict__ W3b,
    const float* __restrict__ b1, const float* __restrict__ b2, const float* __restrict__ b3,
    const float* __restrict__ W4, const float* __restrict__ b4, float* __restrict__ out)
{
    __shared__ __align__(16) unsigned short sBuf[4][TW*S1STR];   // 44032 B

    int tid = threadIdx.x;
    int lane = tid & 63, wid = tid >> 6;

    // ---- in-register scan (k_scan folded): tile prefixes from hdr[0..3] ----
    int c0 = hdr[0], c1 = hdr[1], c2 = hdr[2], c3 = hdr[3];
    int t0 = (c0 + 31) >> 5, t1 = (c1 + 31) >> 5, t2 = (c2 + 31) >> 5;
    int q1 = t0, q2 = q1 + t1, q3 = q2 + t2, total = q3 + ((c3 + 31) >> 5);

    int bi = blockIdx.x;
    int tileId, eBeg, eEnd;
    if (bi < P1BLOCKS){
        // XCD-chunked: each of 8 XCDs owns a contiguous 384-tile range;
        // the 4 waves of a block take 4 consecutive tiles (same species).
        tileId = (bi & 7) * (P1TILES/8) + (bi >> 3) * 4 + wid;   // < 3072 <= total
        eBeg = 0; eEnd = NE;
    } else {
        int u = (bi - P1BLOCKS) * 4 + wid;
        tileId = P1TILES + (u >> 3);
        eBeg = u & 7; eEnd = eBeg + 1;
        if (tileId >= total) return;
    }

    int s = (tileId >= q3) ? 3 : (tileId >= q2) ? 2 : (tileId >= q1) ? 1 : 0;
    int tb = (s == 0) ? 0 : (s == 1) ? q1 : (s == 2) ? q2 : q3;
    int cs = (s == 0) ? c0 : (s == 1) ? c1 : (s == 2) ? c2 : c3;
    int rowBase = (tileId - tb) * TW;
    const int* myIdx = idx + s * BUCKET_CAP + rowBase;
    int nValid = cs - rowBase; if (nValid > TW) nValid = TW; if (nValid < 0) nValid = 0;

    int m = lane & 15, quad = lane >> 4;
    unsigned short (*X1)[S1STR] = (unsigned short (*)[S1STR])sBuf[wid];
    unsigned short (*X2)[S2STR] = (unsigned short (*)[S2STR])sBuf[wid];

    // ---- layer-1 A fragments from global AEV (fp32->fp16), e-invariant ----
    h8v A1[2][12];
    #pragma unroll
    for (int mt = 0; mt < 2; mt++){
        int slot = mt*16 + m;
        int atom = myIdx[(slot < nValid) ? slot : 0];         // guarded pad
        if ((unsigned)atom >= N_ATOMS) atom = 0;              // clamp stale reads
        const float* ap = aev + (size_t)atom * D0 + quad*8;
        #pragma unroll
        for (int kt = 0; kt < 12; kt++){
            float4 u = *(const float4*)(ap + kt*32);
            float4 v = *(const float4*)(ap + kt*32 + 4);
            h8v f;
            f[0] = (_Float16)u.x; f[1] = (_Float16)u.y; f[2] = (_Float16)u.z; f[3] = (_Float16)u.w;
            f[4] = (_Float16)v.x; f[5] = (_Float16)v.y; f[6] = (_Float16)v.z; f[7] = (_Float16)v.w;
            A1[mt][kt] = f;
        }
    }

    float e0[4] = {0.f,0.f,0.f,0.f};
    float e1[4] = {0.f,0.f,0.f,0.f};

    #pragma unroll 1
    for (int e = eBeg; e < eEnd; e++){
        int net = s * NE + e;

        // ---------- layer 1: A1(regs) [K=384] -> X1 [N=160] ----------
        // 3-buffer half-nt rotation: halves h=2nt(kt0-5), 2nt+1(kt6-11) live in
        // Bb[h%3]; next half prefetched into the free buffer before each MFMA
        // batch. 72 VGPRs static (vs 96 ping-pong), 6-12 loads in flight.
        {
            const unsigned short* wf = W1b + (size_t)net * (D0*D1) + lane*8;
            float bc = b1[net*D1 + m];                        // bias for nt=0
            h8v Bb[3][6];
            #pragma unroll
            for (int kt = 0; kt < 6; kt++) Bb[0][kt] = *(const h8v*)(wf + kt*512);
            #pragma unroll
            for (int kt = 0; kt < 6; kt++) Bb[1][kt] = *(const h8v*)(wf + (6+kt)*512);
            #pragma unroll
            for (int nt = 0; nt < 10; nt++){
                int h0 = (2*nt) % 3, h1 = (2*nt + 1) % 3, p0 = (2*nt + 2) % 3;
                float bn = 0.f;
                if (nt < 9){                                  // prefetch nt+1 kt0-5
                    const unsigned short* bp = wf + (nt+1)*6144;
                    #pragma unroll
                    for (int kt = 0; kt < 6; kt++) Bb[p0][kt] = *(const h8v*)(bp + kt*512);
                    bn = b1[net*D1 + (nt+1)*16 + m];          // prefetch next bias
                }
                f4v a0e = {bc, bc, bc, bc}, a1e = a0e;
                f4v a0o = {0.f,0.f,0.f,0.f}, a1o = a0o;
                #pragma unroll
                for (int kt = 0; kt < 6; kt += 2){
                    a0e = __builtin_amdgcn_mfma_f32_16x16x32_f16(A1[0][kt],   Bb[h0][kt],   a0e, 0, 0, 0);
                    a1e = __builtin_amdgcn_mfma_f32_16x16x32_f16(A1[1][kt],   Bb[h0][kt],   a1e, 0, 0, 0);
                    a0o = __builtin_amdgcn_mfma_f32_16x16x32_f16(A1[0][kt+1], Bb[h0][kt+1], a0o, 0, 0, 0);
                    a1o = __builtin_amdgcn_mfma_f32_16x16x32_f16(A1[1][kt+1], Bb[h0][kt+1], a1o, 0, 0, 0);
                }
                if (nt < 9){                                  // prefetch nt+1 kt6-11 into h0
                    const unsigned short* bp = wf + (nt+1)*6144 + 6*512;
                    #pragma unroll
                    for (int kt = 0; kt < 6; kt++) Bb[h0][kt] = *(const h8v*)(bp + kt*512);
                }
                #pragma unroll
                for (int kt = 0; kt < 6; kt += 2){
                    a0e = __builtin_amdgcn_mfma_f32_16x16x32_f16(A1[0][6+kt],   Bb[h1][kt],   a0e, 0, 0, 0);
                    a1e = __builtin_amdgcn_mfma_f32_16x16x32_f16(A1[1][6+kt],   Bb[h1][kt],   a1e, 0, 0, 0);
                    a0o = __builtin_amdgcn_mfma_f32_16x16x32_f16(A1[0][6+kt+1], Bb[h1][kt+1], a0o, 0, 0, 0);
                    a1o = __builtin_amdgcn_mfma_f32_16x16x32_f16(A1[1][6+kt+1], Bb[h1][kt+1], a1o, 0, 0, 0);
                }
                f4v a0 = a0e + a0o, a1 = a1e + a1o;
                #pragma unroll
                for (int r = 0; r < 4; r++){
                    X1[quad*4 + r][nt*16 + m]      = f2h(celu01(a0[r]));
                    X1[16 + quad*4 + r][nt*16 + m] = f2h(celu01(a1[r]));
                }
                bc = bn;
            }
        }

        // ---------- layer 2: X1 [K=160] -> X2 [N=128] ----------
        {
            h8v A2[2][5];
            #pragma unroll
            for (int mt = 0; mt < 2; mt++)
                #pragma unroll
                for (int kt = 0; kt < 5; kt++)
                    A2[mt][kt] = *(const h8v*)&X1[mt*16 + m][kt*32 + quad*8];
            const unsigned short* wf = W2b + (size_t)net * (D1*D2) + lane*8;
            float bc = b2[net*D2 + m];
            h8v Bb[2][5];
            #pragma unroll
            for (int kt = 0; kt < 5; kt++) Bb[0][kt] = *(const h8v*)(wf + kt*512);
            #pragma unroll
            for (int nt = 0; nt < 8; nt++){
                int cur = nt & 1, nxt = cur ^ 1;
                float bn = 0.f;
                if (nt < 7){
                    const unsigned short* bp = wf + (nt+1)*2560;
                    #pragma unroll
                    for (int kt = 0; kt < 5; kt++) Bb[nxt][kt] = *(const h8v*)(bp + kt*512);
                    bn = b2[net*D2 + (nt+1)*16 + m];
                }
                f4v a0e = {bc, bc, bc, bc}, a1e = a0e;
                f4v a0o = {0.f,0.f,0.f,0.f}, a1o = a0o;
                #pragma unroll
                for (int kt = 0; kt < 5; kt++){
                    if ((kt & 1) == 0){
                        a0e = __builtin_amdgcn_mfma_f32_16x16x32_f16(A2[0][kt], Bb[cur][kt], a0e, 0, 0, 0);
                        a1e = __builtin_amdgcn_mfma_f32_16x16x32_f16(A2[1][kt], Bb[cur][kt], a1e, 0, 0, 0);
                    } else {
                        a0o = __builtin_amdgcn_mfma_f32_16x16x32_f16(A2[0][kt], Bb[cur][kt], a0o, 0, 0, 0);
                        a1o = __builtin_amdgcn_mfma_f32_16x16x32_f16(A2[1][kt], Bb[cur][kt], a1o, 0, 0, 0);
                    }
                }
                f4v a0 = a0e + a0o, a1 = a1e + a1o;
                #pragma unroll
                for (int r = 0; r < 4; r++){
                    X2[quad*4 + r][nt*16 + m]      = f2h(celu01(a0[r]));
                    X2[16 + quad*4 + r][nt*16 + m] = f2h(celu01(a1[r]));
                }
                bc = bn;
            }
        }

        // ---------- layer 3 + 4 fused: X2 [K=128] -> per-lane partial energies ----------
        {
            h8v A3[2][4];
            #pragma unroll
            for (int mt = 0; mt < 2; mt++)
                #pragma unroll
                for (int kt = 0; kt < 4; kt++)
                    A3[mt][kt] = *(const h8v*)&X2[mt*16 + m][kt*32 + quad*8];
            const unsigned short* wf = W3b + (size_t)net * (D2*D3) + lane*8;
            const float* w4 = W4 + net * D3;
            float bc = b3[net*D3 + m];
            float wc = w4[m];
            h8v Bb[2][4];
            #pragma unroll
            for (int kt = 0; kt < 4; kt++) Bb[0][kt] = *(const h8v*)(wf + kt*512);
            #pragma unroll
            for (int nt = 0; nt < 6; nt++){
                int cur = nt & 1, nxt = cur ^ 1;
                float bn = 0.f, wn = 0.f;
                if (nt < 5){
                    const unsigned short* bp = wf + (nt+1)*2048;
                    #pragma unroll
                    for (int kt = 0; kt < 4; kt++) Bb[nxt][kt] = *(const h8v*)(bp + kt*512);
                    bn = b3[net*D3 + (nt+1)*16 + m];
                    wn = w4[(nt+1)*16 + m];
                }
                f4v a0e = {bc, bc, bc, bc}, a1e = a0e;
                f4v a0o = {0.f,0.f,0.f,0.f}, a1o = a0o;
                #pragma unroll
                for (int kt = 0; kt < 4; kt += 2){
                    a0e = __builtin_amdgcn_mfma_f32_16x16x32_f16(A3[0][kt],   Bb[cur][kt],   a0e, 0, 0, 0);
                    a1e = __builtin_amdgcn_mfma_f32_16x16x32_f16(A3[1][kt],   Bb[cur][kt],   a1e, 0, 0, 0);
                    a0o = __builtin_amdgcn_mfma_f32_16x16x32_f16(A3[0][kt+1], Bb[cur][kt+1], a0o, 0, 0, 0);
                    a1o = __builtin_amdgcn_mfma_f32_16x16x32_f16(A3[1][kt+1], Bb[cur][kt+1], a1o, 0, 0, 0);
                }
                f4v a0 = a0e + a0o, a1 = a1e + a1o;
                // deferred reduction: per-lane fmaf only; full reduce once at end
                #pragma unroll
                for (int r = 0; r < 4; r++){
                    e0[r] = fmaf(celu01(a0[r]), wc, e0[r]);
                    e1[r] = fmaf(celu01(a1[r]), wc, e1[r]);
                }
                bc = bn; wc = wn;
            }
        }
    }

    // ---- final: mask padded atoms, single 6-shuffle wave reduction, one atomic ----
    {
        float tot = 0.f;
        #pragma unroll
        for (int r = 0; r < 4; r++){
            tot += (quad*4 + r      < nValid) ? e0[r] : 0.f;
            tot += (16 + quad*4 + r < nValid) ? e1[r] : 0.f;
        }
        tot += __shfl_xor(tot, 1, 64);
        tot += __shfl_xor(tot, 2, 64);
        tot += __shfl_xor(tot, 4, 64);
        tot += __shfl_xor(tot, 8, 64);
        tot += __shfl_xor(tot, 16, 64);
        tot += __shfl_xor(tot, 32, 64);
        if (lane == 0 && nValid > 0){
            float sb4 = 0.f;
            for (int e = eBeg; e < eEnd; e++) sb4 += b4[s*NE + e];
            atomicAdd(out, (tot + (float)nValid * sb4) * 0.125f);
        }
    }
}

extern "C" void kernel_launch(void* const* d_in, const int* in_sizes, int n_in,
                              void* d_out, int out_size, void* d_ws, size_t ws_size,
                              hipStream_t stream){
    const float* aev     = (const float*)d_in[0];
    const int*   species = (const int*)  d_in[1];
    const float* W1 = (const float*)d_in[2];
    const float* b1 = (const float*)d_in[3];
    const float* W2 = (const float*)d_in[4];
    const float* b2 = (const float*)d_in[5];
    const float* W3 = (const float*)d_in[6];
    const float* b3 = (const float*)d_in[7];
    const float* W4 = (const float*)d_in[8];
    const float* b4 = (const float*)d_in[9];
    float* out = (float*)d_out;

    int* hdr = (int*)d_ws;
    int* idx = (int*)((char*)d_ws + IDX_OFF_B);
    unsigned short* W1b = (unsigned short*)((char*)d_ws + W1B_OFF);
    unsigned short* W2b = (unsigned short*)((char*)d_ws + W2B_OFF);
    unsigned short* W3b = (unsigned short*)((char*)d_ws + W3B_OFF);

    k_init   <<<1, 64, 0, stream>>>(hdr, out);
    k_scatter<<<(N_ATOMS + 255)/256, 256, 0, stream>>>(species, hdr, idx);
    int convTot = W1_TOT + W2_TOT + W3_TOT;
    k_convert<<<(convTot + 255)/256, 256, 0, stream>>>(W1, W2, W3, W1b, W2b, W3b);
    k_mlp    <<<GRID_MLP, 256, 0, stream>>>(aev, hdr, idx, W1b, W2b, W3b,
                                            b1, b2, b3, W4, b4, out);
}